// Round 1
// baseline (528.060 us; speedup 1.0000x reference)
//
#include <hip/hip_runtime.h>
#include <cstddef>

// Problem constants (reference): B=2048, N=64, C_IN=512, C_H=128, NUM_CLASSES=2, E=1024
#define NN   64
#define CIN  512
#define CH   128

#define SYS  132   // padded stride for 128-wide LDS tiles
#define SXS  65    // padded stride for 64-wide LDS tiles

// ---------------------------------------------------------------------------
// Kernel 1: build normalized adjacency A[d][s] (64x64) in d_ws.
// A = D^-1/2 (Adj + I) D^-1/2 with deg counted on dst (incl. self loops).
// ---------------------------------------------------------------------------
__global__ __launch_bounds__(256) void build_adj(const int* __restrict__ ei, int E,
                                                 float* __restrict__ A) {
    __shared__ float sdeg[NN];
    __shared__ float snorm[NN];
    __shared__ float sA[NN * NN];
    const int t = threadIdx.x;
    if (t < NN) sdeg[t] = 0.f;
    for (int i = t; i < NN * NN; i += 256) sA[i] = 0.f;
    __syncthreads();
    for (int e = t; e < E; e += 256) {
        int d = ei[E + e];
        atomicAdd(&sdeg[d], 1.0f);
    }
    __syncthreads();
    if (t < NN) snorm[t] = rsqrtf(sdeg[t] + 1.0f);  // +1 self-loop, deg>=1
    __syncthreads();
    for (int e = t; e < E; e += 256) {
        int s = ei[e], d = ei[E + e];
        atomicAdd(&sA[d * NN + s], snorm[s] * snorm[d]);
    }
    if (t < NN) atomicAdd(&sA[t * NN + t], snorm[t] * snorm[t]);
    __syncthreads();
    for (int i = t; i < NN * NN; i += 256) A[i] = sA[i];
}

// ---------------------------------------------------------------------------
// Kernel 2: fully fused per-batch GCN. One block per batch element.
//   Y1 = X[b] @ W1            (64x512 @ 512x128, LDS-staged)
//   H1 = relu(A @ Y1 + b1)    (in-LDS aggregation)
//   Y2 = H1 @ W2              (64x128 @ 128x128)
//   H2 = relu(A @ Y2 + b2)    (kept in registers)
//   out[b] = H2.flat @ fcW + fcb  (block reduction)
// Thread map: tc=t&15 -> cols [tc*8, tc*8+8); tr=t>>4 -> rows {tr+16j}.
// ---------------------------------------------------------------------------
__global__ __launch_bounds__(256) void fused_gcn(
    const float* __restrict__ x,  const float* __restrict__ Ag,
    const float* __restrict__ W1, const float* __restrict__ b1,
    const float* __restrict__ W2, const float* __restrict__ b2,
    const float* __restrict__ fcW, const float* __restrict__ fcb,
    float* __restrict__ out)
{
    __shared__ float sA[NN * NN];     // 16 KB adjacency
    __shared__ float sY[NN * SYS];    // 33 KB pre-agg buffer
    __shared__ float sH[NN * SYS];    // 33 KB post-agg buffer
    __shared__ float sX[NN * SXS];    // 16.25 KB X chunk
    __shared__ float sW[NN * SYS];    // 33 KB weight chunk
    __shared__ float sred[8];

    const int t  = threadIdx.x;
    const int b  = blockIdx.x;
    const int tc = t & 15;
    const int tr = t >> 4;
    const int c0 = tc * 8;

    for (int i = t; i < NN * NN; i += 256) sA[i] = Ag[i];

    const float* __restrict__ xb = x + (size_t)b * NN * CIN;

    float acc[4][8];
    #pragma unroll
    for (int j = 0; j < 4; ++j)
        #pragma unroll
        for (int i = 0; i < 8; ++i) acc[j][i] = 0.f;

    // ---- GEMM1: Y1 = X[b] @ W1, K staged in chunks of 64 ----
    for (int kc = 0; kc < CIN / 64; ++kc) {
        #pragma unroll
        for (int u = 0; u < 4; ++u) {          // stage X chunk [64][64]
            int i4  = t + 256 * u;
            int row = i4 >> 4;
            int cc  = (i4 & 15) << 2;
            const float4 v = *reinterpret_cast<const float4*>(xb + (size_t)row * CIN + kc * 64 + cc);
            float* d = &sX[row * SXS + cc];
            d[0] = v.x; d[1] = v.y; d[2] = v.z; d[3] = v.w;
        }
        #pragma unroll
        for (int u = 0; u < 8; ++u) {          // stage W1 chunk [64][128]
            int i4  = t + 256 * u;
            int row = i4 >> 5;
            int cc  = (i4 & 31) << 2;
            *reinterpret_cast<float4*>(&sW[row * SYS + cc]) =
                *reinterpret_cast<const float4*>(W1 + (size_t)(kc * 64 + row) * CH + cc);
        }
        __syncthreads();
        #pragma unroll 2
        for (int k = 0; k < 64; ++k) {
            float xv[4];
            #pragma unroll
            for (int j = 0; j < 4; ++j) xv[j] = sX[(tr + 16 * j) * SXS + k];
            const float4 w0 = *reinterpret_cast<const float4*>(&sW[k * SYS + c0]);
            const float4 w1 = *reinterpret_cast<const float4*>(&sW[k * SYS + c0 + 4]);
            const float wv[8] = {w0.x, w0.y, w0.z, w0.w, w1.x, w1.y, w1.z, w1.w};
            #pragma unroll
            for (int j = 0; j < 4; ++j)
                #pragma unroll
                for (int i = 0; i < 8; ++i)
                    acc[j][i] = fmaf(xv[j], wv[i], acc[j][i]);
        }
        __syncthreads();
    }

    #pragma unroll
    for (int j = 0; j < 4; ++j) {              // Y1 -> sY
        float* d = &sY[(tr + 16 * j) * SYS + c0];
        #pragma unroll
        for (int i = 0; i < 8; ++i) d[i] = acc[j][i];
    }
    __syncthreads();

    // ---- Agg1: H1 = relu(A @ Y1 + b1) -> sH ----
    {
        float h[4][8];
        #pragma unroll
        for (int j = 0; j < 4; ++j)
            #pragma unroll
            for (int i = 0; i < 8; ++i) h[j][i] = 0.f;
        for (int m = 0; m < NN; ++m) {
            float av[4];
            #pragma unroll
            for (int j = 0; j < 4; ++j) av[j] = sA[(tr + 16 * j) * NN + m];
            const float4 y0 = *reinterpret_cast<const float4*>(&sY[m * SYS + c0]);
            const float4 y1 = *reinterpret_cast<const float4*>(&sY[m * SYS + c0 + 4]);
            const float yv[8] = {y0.x, y0.y, y0.z, y0.w, y1.x, y1.y, y1.z, y1.w};
            #pragma unroll
            for (int j = 0; j < 4; ++j)
                #pragma unroll
                for (int i = 0; i < 8; ++i)
                    h[j][i] = fmaf(av[j], yv[i], h[j][i]);
        }
        #pragma unroll
        for (int j = 0; j < 4; ++j) {
            float* d = &sH[(tr + 16 * j) * SYS + c0];
            #pragma unroll
            for (int i = 0; i < 8; ++i) {
                float v = h[j][i] + b1[c0 + i];
                d[i] = v > 0.f ? v : 0.f;
            }
        }
    }
    __syncthreads();

    // ---- GEMM2: Y2 = H1 @ W2 ----
    #pragma unroll
    for (int j = 0; j < 4; ++j)
        #pragma unroll
        for (int i = 0; i < 8; ++i) acc[j][i] = 0.f;

    for (int kc = 0; kc < CH / 64; ++kc) {
        #pragma unroll
        for (int u = 0; u < 8; ++u) {          // stage W2 chunk [64][128]
            int i4  = t + 256 * u;
            int row = i4 >> 5;
            int cc  = (i4 & 31) << 2;
            *reinterpret_cast<float4*>(&sW[row * SYS + cc]) =
                *reinterpret_cast<const float4*>(W2 + (size_t)(kc * 64 + row) * CH + cc);
        }
        __syncthreads();
        #pragma unroll 2
        for (int k = 0; k < 64; ++k) {
            float xv[4];
            #pragma unroll
            for (int j = 0; j < 4; ++j) xv[j] = sH[(tr + 16 * j) * SYS + kc * 64 + k];
            const float4 w0 = *reinterpret_cast<const float4*>(&sW[k * SYS + c0]);
            const float4 w1 = *reinterpret_cast<const float4*>(&sW[k * SYS + c0 + 4]);
            const float wv[8] = {w0.x, w0.y, w0.z, w0.w, w1.x, w1.y, w1.z, w1.w};
            #pragma unroll
            for (int j = 0; j < 4; ++j)
                #pragma unroll
                for (int i = 0; i < 8; ++i)
                    acc[j][i] = fmaf(xv[j], wv[i], acc[j][i]);
        }
        __syncthreads();
    }

    #pragma unroll
    for (int j = 0; j < 4; ++j) {              // Y2 -> sY (free after agg1)
        float* d = &sY[(tr + 16 * j) * SYS + c0];
        #pragma unroll
        for (int i = 0; i < 8; ++i) d[i] = acc[j][i];
    }
    __syncthreads();

    // ---- Agg2 + bias + relu (registers) + FC partials ----
    float p0 = 0.f, p1 = 0.f;
    {
        float h[4][8];
        #pragma unroll
        for (int j = 0; j < 4; ++j)
            #pragma unroll
            for (int i = 0; i < 8; ++i) h[j][i] = 0.f;
        for (int m = 0; m < NN; ++m) {
            float av[4];
            #pragma unroll
            for (int j = 0; j < 4; ++j) av[j] = sA[(tr + 16 * j) * NN + m];
            const float4 y0 = *reinterpret_cast<const float4*>(&sY[m * SYS + c0]);
            const float4 y1 = *reinterpret_cast<const float4*>(&sY[m * SYS + c0 + 4]);
            const float yv[8] = {y0.x, y0.y, y0.z, y0.w, y1.x, y1.y, y1.z, y1.w};
            #pragma unroll
            for (int j = 0; j < 4; ++j)
                #pragma unroll
                for (int i = 0; i < 8; ++i)
                    h[j][i] = fmaf(av[j], yv[i], h[j][i]);
        }
        #pragma unroll
        for (int j = 0; j < 4; ++j) {
            int r = tr + 16 * j;
            #pragma unroll
            for (int i = 0; i < 8; ++i) {
                float v = h[j][i] + b2[c0 + i];
                v = v > 0.f ? v : 0.f;
                const float* fw = fcW + (size_t)(r * CH + c0 + i) * 2;
                p0 = fmaf(v, fw[0], p0);
                p1 = fmaf(v, fw[1], p1);
            }
        }
    }
    #pragma unroll
    for (int off = 32; off > 0; off >>= 1) {
        p0 += __shfl_down(p0, off);
        p1 += __shfl_down(p1, off);
    }
    if ((t & 63) == 0) { sred[(t >> 6) * 2] = p0; sred[(t >> 6) * 2 + 1] = p1; }
    __syncthreads();
    if (t == 0) {
        out[(size_t)b * 2 + 0] = sred[0] + sred[2] + sred[4] + sred[6] + fcb[0];
        out[(size_t)b * 2 + 1] = sred[1] + sred[3] + sred[5] + sred[7] + fcb[1];
    }
}

// ---------------------------------------------------------------------------
extern "C" void kernel_launch(void* const* d_in, const int* in_sizes, int n_in,
                              void* d_out, int out_size, void* d_ws, size_t ws_size,
                              hipStream_t stream) {
    const float* x   = (const float*)d_in[0];
    const int*   ei  = (const int*)d_in[1];
    const float* W1  = (const float*)d_in[2];
    const float* b1  = (const float*)d_in[3];
    const float* W2  = (const float*)d_in[4];
    const float* b2  = (const float*)d_in[5];
    const float* fcW = (const float*)d_in[6];
    const float* fcb = (const float*)d_in[7];
    float* outp = (float*)d_out;
    float* A = (float*)d_ws;   // 64*64 floats = 16 KB

    const int E  = in_sizes[1] / 2;
    const int Bn = in_sizes[0] / (NN * CIN);

    build_adj<<<1, 256, 0, stream>>>(ei, E, A);
    fused_gcn<<<Bn, 256, 0, stream>>>(x, A, W1, b1, W2, b2, fcW, fcb, outp);
}

// Round 2
// 131.806 us; speedup vs baseline: 4.0064x; 4.0064x over previous
//
#include <hip/hip_runtime.h>
#include <cstddef>

// B=2048, N=64, C_IN=512, C_H=128, NUM_CLASSES=2, E=1024
#define NN   64
#define CIN  512
#define CH   128

typedef unsigned short ushort_t;
typedef __attribute__((ext_vector_type(8))) short bf16x8;
typedef __attribute__((ext_vector_type(4))) short bf16x4;
typedef __attribute__((ext_vector_type(4))) float f32x4;

__device__ __forceinline__ ushort_t f2bf(float f) {          // RN-even fp32->bf16
    union { float f; unsigned u; } v; v.f = f;
    unsigned r = v.u + 0x7fffu + ((v.u >> 16) & 1u);
    return (ushort_t)(r >> 16);
}
__device__ __forceinline__ float bf2f(ushort_t b) {
    union { unsigned u; float f; } v; v.u = ((unsigned)b) << 16;
    return v.f;
}

// ---------------------------------------------------------------------------
// Kernel 1: build normalized adjacency A (64x64), split hi/lo bf16 into ws.
// ---------------------------------------------------------------------------
__global__ __launch_bounds__(256) void build_adj(const int* __restrict__ ei, int E,
                                                 ushort_t* __restrict__ Ah,
                                                 ushort_t* __restrict__ Al) {
    __shared__ float sdeg[NN];
    __shared__ float snorm[NN];
    __shared__ float sA[NN * NN];
    const int t = threadIdx.x;
    if (t < NN) sdeg[t] = 0.f;
    for (int i = t; i < NN * NN; i += 256) sA[i] = 0.f;
    __syncthreads();
    for (int e = t; e < E; e += 256) atomicAdd(&sdeg[ei[E + e]], 1.0f);
    __syncthreads();
    if (t < NN) snorm[t] = rsqrtf(sdeg[t] + 1.0f);
    __syncthreads();
    for (int e = t; e < E; e += 256) {
        int s = ei[e], d = ei[E + e];
        atomicAdd(&sA[d * NN + s], snorm[s] * snorm[d]);
    }
    if (t < NN) atomicAdd(&sA[t * NN + t], snorm[t] * snorm[t]);
    __syncthreads();
    for (int i = t; i < NN * NN; i += 256) {
        float a = sA[i];
        ushort_t h = f2bf(a);
        Ah[i] = h;
        Al[i] = f2bf(a - bf2f(h));
    }
}

// ---------------------------------------------------------------------------
// Kernel 2: transpose + hi/lo-split W1 -> W1t[c][k], W2 -> W2t[c][k] (bf16).
// ---------------------------------------------------------------------------
__global__ __launch_bounds__(256) void prep_w(const float* __restrict__ W1,
                                              const float* __restrict__ W2,
                                              ushort_t* __restrict__ W1h, ushort_t* __restrict__ W1l,
                                              ushort_t* __restrict__ W2h, ushort_t* __restrict__ W2l) {
    const int idx = blockIdx.x * 256 + threadIdx.x;
    const int stride = gridDim.x * 256;
    for (int i = idx; i < CIN * CH; i += stride) {
        int k = i / CH, c = i % CH;        // coalesced read along c
        float v = W1[i];
        ushort_t h = f2bf(v);
        W1h[c * CIN + k] = h;
        W1l[c * CIN + k] = f2bf(v - bf2f(h));
    }
    for (int i = idx; i < CH * CH; i += stride) {
        int k = i / CH, c = i % CH;
        float v = W2[i];
        ushort_t h = f2bf(v);
        W2h[c * CH + k] = h;
        W2l[c * CH + k] = f2bf(v - bf2f(h));
    }
}

// ---------------------------------------------------------------------------
// Kernel 3: fully fused per-batch GCN via MFMA (split-bf16 emulated fp32).
// 512 threads = 8 waves; wave w owns rows [ (w&3)*16 ) x cols [ (w>>2)*64 ).
// MFMA 16x16x32 bf16: A-frag lane: row=l&15, k=(l>>4)*8+j ;
//                     B-frag lane: col=l&15, k=(l>>4)*8+j ;
//                     C/D: col=l&15, row=(l>>4)*4+reg   (m89-verified).
// LDS (73.7 KB, 2 blocks/CU):
//   sXh/sXl [64][72]  (aliased by sH1 [64][136] after GEMM1)
//   sWh/sWl [128][72]  sYt [128][72]
// ---------------------------------------------------------------------------
__global__ __launch_bounds__(512, 4) void fused_gcn(
    const float* __restrict__ x,
    const ushort_t* __restrict__ Ah, const ushort_t* __restrict__ Al,
    const ushort_t* __restrict__ W1h, const ushort_t* __restrict__ W1l,
    const ushort_t* __restrict__ W2h, const ushort_t* __restrict__ W2l,
    const float* __restrict__ b1, const float* __restrict__ b2,
    const float* __restrict__ fcW, const float* __restrict__ fcb,
    float* __restrict__ out)
{
    __shared__ ushort_t lds[36864];     // 73728 B
    __shared__ float sred[16];
    ushort_t* sXh = lds;                // [64][72]
    ushort_t* sXl = lds + 4608;         // [64][72]
    ushort_t* sH1 = lds;                // [64][136] aliases sX (8704 <= 9216)
    ushort_t* sWh = lds + 9216;         // [128][72]
    ushort_t* sWl = lds + 18432;        // [128][72]
    ushort_t* sYt = lds + 27648;        // [128][72]  (Y^T: [col][row])

    const int t  = threadIdx.x;
    const int b  = blockIdx.x;
    const int l  = t & 63;
    const int w  = t >> 6;
    const int wr = w & 3;               // row-tile (rows wr*16..)
    const int wc = w >> 1 >> 1;         // col-half (cols wc*64..)
    const int lr = l & 15;
    const int lk = l >> 4;

    const float* __restrict__ xb = x + (size_t)b * NN * CIN;

    const int xrow = t >> 3;            // 0..63
    const int xk   = (t & 7) * 8;       // 0..56

    f32x4 acc[4];
    #pragma unroll
    for (int ct = 0; ct < 4; ++ct)
        #pragma unroll
        for (int i = 0; i < 4; ++i) acc[ct][i] = 0.f;

    // ======== GEMM1: Y1 = X @ W1  (3-pass split bf16) ========
    for (int kc = 0; kc < CIN / 64; ++kc) {
        {   // stage X chunk [64][64] -> hi/lo
            const float* src = xb + (size_t)xrow * CIN + kc * 64 + xk;
            const float4 v0 = *reinterpret_cast<const float4*>(src);
            const float4 v1 = *reinterpret_cast<const float4*>(src + 4);
            const float xv[8] = {v0.x, v0.y, v0.z, v0.w, v1.x, v1.y, v1.z, v1.w};
            bf16x8 hv, lv;
            #pragma unroll
            for (int j = 0; j < 8; ++j) {
                ushort_t h = f2bf(xv[j]);
                hv[j] = (short)h;
                lv[j] = (short)f2bf(xv[j] - bf2f(h));
            }
            *reinterpret_cast<bf16x8*>(&sXh[xrow * 72 + xk]) = hv;
            *reinterpret_cast<bf16x8*>(&sXl[xrow * 72 + xk]) = lv;
        }
        #pragma unroll
        for (int u = 0; u < 2; ++u) {   // stage W1t chunk [128 cols][64 k]
            int idx  = u * 512 + t;
            int rowc = idx >> 3;
            int kq   = (idx & 7) * 8;
            *reinterpret_cast<bf16x8*>(&sWh[rowc * 72 + kq]) =
                *reinterpret_cast<const bf16x8*>(W1h + (size_t)rowc * CIN + kc * 64 + kq);
            *reinterpret_cast<bf16x8*>(&sWl[rowc * 72 + kq]) =
                *reinterpret_cast<const bf16x8*>(W1l + (size_t)rowc * CIN + kc * 64 + kq);
        }
        __syncthreads();
        #pragma unroll
        for (int ks = 0; ks < 2; ++ks) {
            const int ko = ks * 32 + lk * 8;
            bf16x8 xh = *reinterpret_cast<const bf16x8*>(&sXh[(wr * 16 + lr) * 72 + ko]);
            bf16x8 xl = *reinterpret_cast<const bf16x8*>(&sXl[(wr * 16 + lr) * 72 + ko]);
            #pragma unroll
            for (int ct = 0; ct < 4; ++ct) {
                const int c = wc * 64 + ct * 16 + lr;
                bf16x8 wh = *reinterpret_cast<const bf16x8*>(&sWh[c * 72 + ko]);
                bf16x8 wl = *reinterpret_cast<const bf16x8*>(&sWl[c * 72 + ko]);
                acc[ct] = __builtin_amdgcn_mfma_f32_16x16x32_bf16(xh, wh, acc[ct], 0, 0, 0);
                acc[ct] = __builtin_amdgcn_mfma_f32_16x16x32_bf16(xl, wh, acc[ct], 0, 0, 0);
                acc[ct] = __builtin_amdgcn_mfma_f32_16x16x32_bf16(xh, wl, acc[ct], 0, 0, 0);
            }
        }
        __syncthreads();
    }

    // Y1 -> sYt[col][row] (single bf16)
    #pragma unroll
    for (int ct = 0; ct < 4; ++ct) {
        const int c = wc * 64 + ct * 16 + lr;
        bf16x4 yv;
        #pragma unroll
        for (int r = 0; r < 4; ++r) yv[r] = (short)f2bf(acc[ct][r]);
        *reinterpret_cast<bf16x4*>(&sYt[c * 72 + wr * 16 + lk * 4]) = yv;
    }
    __syncthreads();

    // ======== Agg1: H1 = relu(A @ Y1 + b1)  (2-pass: Ah,Al) ========
    bf16x8 ahf[2], alf[2];
    #pragma unroll
    for (int ks = 0; ks < 2; ++ks) {
        const int ko = ks * 32 + lk * 8;
        ahf[ks] = *reinterpret_cast<const bf16x8*>(Ah + (wr * 16 + lr) * NN + ko);
        alf[ks] = *reinterpret_cast<const bf16x8*>(Al + (wr * 16 + lr) * NN + ko);
    }
    {
        f32x4 hacc[4];
        #pragma unroll
        for (int ct = 0; ct < 4; ++ct)
            #pragma unroll
            for (int i = 0; i < 4; ++i) hacc[ct][i] = 0.f;
        #pragma unroll
        for (int ks = 0; ks < 2; ++ks) {
            const int ko = ks * 32 + lk * 8;
            #pragma unroll
            for (int ct = 0; ct < 4; ++ct) {
                const int c = wc * 64 + ct * 16 + lr;
                bf16x8 y = *reinterpret_cast<const bf16x8*>(&sYt[c * 72 + ko]);
                hacc[ct] = __builtin_amdgcn_mfma_f32_16x16x32_bf16(ahf[ks], y, hacc[ct], 0, 0, 0);
                hacc[ct] = __builtin_amdgcn_mfma_f32_16x16x32_bf16(alf[ks], y, hacc[ct], 0, 0, 0);
            }
        }
        // bias + relu -> sH1 row-major [64][136] (single bf16); sH1 aliases sX (dead)
        #pragma unroll
        for (int ct = 0; ct < 4; ++ct) {
            const int c = wc * 64 + ct * 16 + lr;
            const float bias = b1[c];
            #pragma unroll
            for (int r = 0; r < 4; ++r) {
                float v = hacc[ct][r] + bias;
                v = fmaxf(v, 0.f);
                sH1[(wr * 16 + lk * 4 + r) * 136 + c] = f2bf(v);
            }
        }
    }
    __syncthreads();

    // ======== GEMM2: Y2 = H1 @ W2  (2-pass: W2h,W2l) ========
    f32x4 acc2[4];
    #pragma unroll
    for (int ct = 0; ct < 4; ++ct)
        #pragma unroll
        for (int i = 0; i < 4; ++i) acc2[ct][i] = 0.f;

    for (int kc = 0; kc < CH / 64; ++kc) {
        #pragma unroll
        for (int u = 0; u < 2; ++u) {   // stage W2t chunk
            int idx  = u * 512 + t;
            int rowc = idx >> 3;
            int kq   = (idx & 7) * 8;
            *reinterpret_cast<bf16x8*>(&sWh[rowc * 72 + kq]) =
                *reinterpret_cast<const bf16x8*>(W2h + (size_t)rowc * CH + kc * 64 + kq);
            *reinterpret_cast<bf16x8*>(&sWl[rowc * 72 + kq]) =
                *reinterpret_cast<const bf16x8*>(W2l + (size_t)rowc * CH + kc * 64 + kq);
        }
        __syncthreads();
        #pragma unroll
        for (int ks = 0; ks < 2; ++ks) {
            const int ko = ks * 32 + lk * 8;
            bf16x8 hf = *reinterpret_cast<const bf16x8*>(&sH1[(wr * 16 + lr) * 136 + kc * 64 + ko]);
            #pragma unroll
            for (int ct = 0; ct < 4; ++ct) {
                const int c = wc * 64 + ct * 16 + lr;
                bf16x8 wh = *reinterpret_cast<const bf16x8*>(&sWh[c * 72 + ko]);
                bf16x8 wl = *reinterpret_cast<const bf16x8*>(&sWl[c * 72 + ko]);
                acc2[ct] = __builtin_amdgcn_mfma_f32_16x16x32_bf16(hf, wh, acc2[ct], 0, 0, 0);
                acc2[ct] = __builtin_amdgcn_mfma_f32_16x16x32_bf16(hf, wl, acc2[ct], 0, 0, 0);
            }
        }
        __syncthreads();
    }

    // Y2 -> sYt (overwrite; all agg1 reads completed before GEMM2 barriers)
    #pragma unroll
    for (int ct = 0; ct < 4; ++ct) {
        const int c = wc * 64 + ct * 16 + lr;
        bf16x4 yv;
        #pragma unroll
        for (int r = 0; r < 4; ++r) yv[r] = (short)f2bf(acc2[ct][r]);
        *reinterpret_cast<bf16x4*>(&sYt[c * 72 + wr * 16 + lk * 4]) = yv;
    }
    __syncthreads();

    // ======== Agg2 + bias + relu + FC ========
    float p0 = 0.f, p1 = 0.f;
    {
        f32x4 h2[4];
        #pragma unroll
        for (int ct = 0; ct < 4; ++ct)
            #pragma unroll
            for (int i = 0; i < 4; ++i) h2[ct][i] = 0.f;
        #pragma unroll
        for (int ks = 0; ks < 2; ++ks) {
            const int ko = ks * 32 + lk * 8;
            #pragma unroll
            for (int ct = 0; ct < 4; ++ct) {
                const int c = wc * 64 + ct * 16 + lr;
                bf16x8 y = *reinterpret_cast<const bf16x8*>(&sYt[c * 72 + ko]);
                h2[ct] = __builtin_amdgcn_mfma_f32_16x16x32_bf16(ahf[ks], y, h2[ct], 0, 0, 0);
                h2[ct] = __builtin_amdgcn_mfma_f32_16x16x32_bf16(alf[ks], y, h2[ct], 0, 0, 0);
            }
        }
        #pragma unroll
        for (int ct = 0; ct < 4; ++ct) {
            const int c = wc * 64 + ct * 16 + lr;
            const float bias = b2[c];
            #pragma unroll
            for (int r = 0; r < 4; ++r) {
                const int rg = wr * 16 + lk * 4 + r;
                float v = fmaxf(h2[ct][r] + bias, 0.f);
                const float* fw = fcW + ((size_t)(rg * CH + c)) * 2;
                p0 = fmaf(v, fw[0], p0);
                p1 = fmaf(v, fw[1], p1);
            }
        }
    }
    #pragma unroll
    for (int off = 32; off > 0; off >>= 1) {
        p0 += __shfl_down(p0, off);
        p1 += __shfl_down(p1, off);
    }
    if (l == 0) { sred[w * 2] = p0; sred[w * 2 + 1] = p1; }
    __syncthreads();
    if (t == 0) {
        float s0 = fcb[0], s1 = fcb[1];
        #pragma unroll
        for (int i = 0; i < 8; ++i) { s0 += sred[2 * i]; s1 += sred[2 * i + 1]; }
        out[(size_t)b * 2 + 0] = s0;
        out[(size_t)b * 2 + 1] = s1;
    }
}

// ---------------------------------------------------------------------------
extern "C" void kernel_launch(void* const* d_in, const int* in_sizes, int n_in,
                              void* d_out, int out_size, void* d_ws, size_t ws_size,
                              hipStream_t stream) {
    const float* x   = (const float*)d_in[0];
    const int*   ei  = (const int*)d_in[1];
    const float* W1  = (const float*)d_in[2];
    const float* b1  = (const float*)d_in[3];
    const float* W2  = (const float*)d_in[4];
    const float* b2  = (const float*)d_in[5];
    const float* fcW = (const float*)d_in[6];
    const float* fcb = (const float*)d_in[7];
    float* outp = (float*)d_out;

    // ws layout (bf16): Ah,Al [64*64]; W1t h,l [128*512]; W2t h,l [128*128]
    ushort_t* Ah  = (ushort_t*)d_ws;
    ushort_t* Al  = Ah + NN * NN;
    ushort_t* W1h = Al + NN * NN;
    ushort_t* W1l = W1h + CIN * CH;
    ushort_t* W2h = W1l + CIN * CH;
    ushort_t* W2l = W2h + CH * CH;      // total 344064 B

    const int E  = in_sizes[1] / 2;
    const int Bn = in_sizes[0] / (NN * CIN);

    build_adj<<<1, 256, 0, stream>>>(ei, E, Ah, Al);
    prep_w<<<64, 256, 0, stream>>>(W1, W2, W1h, W1l, W2h, W2l);
    fused_gcn<<<Bn, 512, 0, stream>>>(x, Ah, Al, W1h, W1l, W2h, W2l,
                                      b1, b2, fcW, fcb, outp);
}

// Round 3
// 127.284 us; speedup vs baseline: 4.1487x; 1.0355x over previous
//
#include <hip/hip_runtime.h>
#include <cstddef>

// B=2048, N=64, C_IN=512, C_H=128, NUM_CLASSES=2, E=1024
#define NN   64
#define CIN  512
#define CH   128

typedef unsigned short ushort_t;
typedef __attribute__((ext_vector_type(8))) short bf16x8;
typedef __attribute__((ext_vector_type(4))) short bf16x4;
typedef __attribute__((ext_vector_type(4))) float f32x4;

__device__ __forceinline__ ushort_t f2bf(float f) {          // RN-even fp32->bf16
    union { float f; unsigned u; } v; v.f = f;
    unsigned r = v.u + 0x7fffu + ((v.u >> 16) & 1u);
    return (ushort_t)(r >> 16);
}
__device__ __forceinline__ float bf2f(ushort_t b) {
    union { unsigned u; float f; } v; v.u = ((unsigned)b) << 16;
    return v.f;
}

// ---------------------------------------------------------------------------
// Kernel 1: build normalized adjacency A (64x64), split hi/lo bf16 into ws.
// ---------------------------------------------------------------------------
__global__ __launch_bounds__(256) void build_adj(const int* __restrict__ ei, int E,
                                                 ushort_t* __restrict__ Ah,
                                                 ushort_t* __restrict__ Al) {
    __shared__ float sdeg[NN];
    __shared__ float snorm[NN];
    __shared__ float sA[NN * NN];
    const int t = threadIdx.x;
    if (t < NN) sdeg[t] = 0.f;
    for (int i = t; i < NN * NN; i += 256) sA[i] = 0.f;
    __syncthreads();
    for (int e = t; e < E; e += 256) atomicAdd(&sdeg[ei[E + e]], 1.0f);
    __syncthreads();
    if (t < NN) snorm[t] = rsqrtf(sdeg[t] + 1.0f);
    __syncthreads();
    for (int e = t; e < E; e += 256) {
        int s = ei[e], d = ei[E + e];
        atomicAdd(&sA[d * NN + s], snorm[s] * snorm[d]);
    }
    if (t < NN) atomicAdd(&sA[t * NN + t], snorm[t] * snorm[t]);
    __syncthreads();
    for (int i = t; i < NN * NN; i += 256) {
        float a = sA[i];
        ushort_t h = f2bf(a);
        Ah[i] = h;
        Al[i] = f2bf(a - bf2f(h));
    }
}

// ---------------------------------------------------------------------------
// Kernel 2: transpose + hi/lo-split W1 -> W1t[c][k], W2 -> W2t[c][k] (bf16).
// ---------------------------------------------------------------------------
__global__ __launch_bounds__(256) void prep_w(const float* __restrict__ W1,
                                              const float* __restrict__ W2,
                                              ushort_t* __restrict__ W1h, ushort_t* __restrict__ W1l,
                                              ushort_t* __restrict__ W2h, ushort_t* __restrict__ W2l) {
    const int idx = blockIdx.x * 256 + threadIdx.x;
    const int stride = gridDim.x * 256;
    for (int i = idx; i < CIN * CH; i += stride) {
        int k = i / CH, c = i % CH;
        float v = W1[i];
        ushort_t h = f2bf(v);
        W1h[c * CIN + k] = h;
        W1l[c * CIN + k] = f2bf(v - bf2f(h));
    }
    for (int i = idx; i < CH * CH; i += stride) {
        int k = i / CH, c = i % CH;
        float v = W2[i];
        ushort_t h = f2bf(v);
        W2h[c * CH + k] = h;
        W2l[c * CH + k] = f2bf(v - bf2f(h));
    }
}

// ---------------------------------------------------------------------------
// Kernel 3: streaming Y1 = X @ W1 (split-bf16, 3-pass).
// Grid 1024 x 256 thr (4 waves). Tile: 128 rows x 128 cols, K=512 in chunks
// of 64, W chunk double-buffered in LDS w/ register prefetch. X loaded
// fragment-native to registers (per-row 256B segments, L1-coalesced).
// Output: Y1t[b][c][n] bf16 (per-batch transposed = agg1's B-frag layout).
// ---------------------------------------------------------------------------
__global__ __launch_bounds__(256, 2) void gemm1_xw(
    const float* __restrict__ x,
    const ushort_t* __restrict__ W1h, const ushort_t* __restrict__ W1l,
    ushort_t* __restrict__ Y1t)
{
    __shared__ ushort_t sW[2][2][128 * 72];   // [buf][h/l][c][k] 73728 B

    const int t  = threadIdx.x;
    const int l  = t & 63;
    const int w  = t >> 6;
    const int lr = l & 15;
    const int lk = l >> 4;
    const size_t rbase = (size_t)blockIdx.x * 128;

    bf16x8 wreg[2][4];

    // ---- prologue: stage W chunk 0 ----
    #pragma unroll
    for (int u = 0; u < 4; ++u) {
        int q = u * 256 + t, c = q >> 3, kq = (q & 7) * 8;
        wreg[0][u] = *reinterpret_cast<const bf16x8*>(W1h + (size_t)c * CIN + kq);
        wreg[1][u] = *reinterpret_cast<const bf16x8*>(W1l + (size_t)c * CIN + kq);
    }
    #pragma unroll
    for (int u = 0; u < 4; ++u) {
        int q = u * 256 + t, c = q >> 3, kq = (q & 7) * 8;
        *reinterpret_cast<bf16x8*>(&sW[0][0][c * 72 + kq]) = wreg[0][u];
        *reinterpret_cast<bf16x8*>(&sW[0][1][c * 72 + kq]) = wreg[1][u];
    }
    __syncthreads();

    f32x4 acc[2][8];
    #pragma unroll
    for (int rf = 0; rf < 2; ++rf)
        #pragma unroll
        for (int ct = 0; ct < 8; ++ct)
            #pragma unroll
            for (int i = 0; i < 4; ++i) acc[rf][ct][i] = 0.f;

    for (int kc = 0; kc < 8; ++kc) {
        const int cur = kc & 1;
        // issue X loads for this chunk (fragment-native)
        float4 xr[2][2][2];
        #pragma unroll
        for (int rf = 0; rf < 2; ++rf) {
            const float* xp = x + (rbase + w * 32 + rf * 16 + lr) * CIN + kc * 64 + lk * 8;
            xr[rf][0][0] = *reinterpret_cast<const float4*>(xp);
            xr[rf][0][1] = *reinterpret_cast<const float4*>(xp + 4);
            xr[rf][1][0] = *reinterpret_cast<const float4*>(xp + 32);
            xr[rf][1][1] = *reinterpret_cast<const float4*>(xp + 36);
        }
        // issue next W chunk loads (prefetch to regs; written after compute)
        if (kc < 7) {
            #pragma unroll
            for (int u = 0; u < 4; ++u) {
                int q = u * 256 + t, c = q >> 3, kq = (q & 7) * 8;
                wreg[0][u] = *reinterpret_cast<const bf16x8*>(W1h + (size_t)c * CIN + (kc + 1) * 64 + kq);
                wreg[1][u] = *reinterpret_cast<const bf16x8*>(W1l + (size_t)c * CIN + (kc + 1) * 64 + kq);
            }
        }
        // compute
        #pragma unroll
        for (int rf = 0; rf < 2; ++rf) {
            #pragma unroll
            for (int ks = 0; ks < 2; ++ks) {
                const float xv[8] = {xr[rf][ks][0].x, xr[rf][ks][0].y, xr[rf][ks][0].z, xr[rf][ks][0].w,
                                     xr[rf][ks][1].x, xr[rf][ks][1].y, xr[rf][ks][1].z, xr[rf][ks][1].w};
                bf16x8 xh, xl;
                #pragma unroll
                for (int j = 0; j < 8; ++j) {
                    ushort_t h = f2bf(xv[j]);
                    xh[j] = (short)h;
                    xl[j] = (short)f2bf(xv[j] - bf2f(h));
                }
                const int ko = ks * 32 + lk * 8;
                #pragma unroll
                for (int ct = 0; ct < 8; ++ct) {
                    const int c = ct * 16 + lr;
                    bf16x8 wh = *reinterpret_cast<const bf16x8*>(&sW[cur][0][c * 72 + ko]);
                    bf16x8 wl = *reinterpret_cast<const bf16x8*>(&sW[cur][1][c * 72 + ko]);
                    acc[rf][ct] = __builtin_amdgcn_mfma_f32_16x16x32_bf16(xh, wh, acc[rf][ct], 0, 0, 0);
                    acc[rf][ct] = __builtin_amdgcn_mfma_f32_16x16x32_bf16(xl, wh, acc[rf][ct], 0, 0, 0);
                    acc[rf][ct] = __builtin_amdgcn_mfma_f32_16x16x32_bf16(xh, wl, acc[rf][ct], 0, 0, 0);
                }
            }
        }
        // write next chunk into alternate buffer, then one barrier
        if (kc < 7) {
            #pragma unroll
            for (int u = 0; u < 4; ++u) {
                int q = u * 256 + t, c = q >> 3, kq = (q & 7) * 8;
                *reinterpret_cast<bf16x8*>(&sW[cur ^ 1][0][c * 72 + kq]) = wreg[0][u];
                *reinterpret_cast<bf16x8*>(&sW[cur ^ 1][1][c * 72 + kq]) = wreg[1][u];
            }
        }
        __syncthreads();
    }

    // ---- store Y1t[b][c][n] (bf16x4 per fragment) ----
    #pragma unroll
    for (int rf = 0; rf < 2; ++rf) {
        const size_t gr = rbase + w * 32 + rf * 16 + lk * 4;
        const size_t b  = gr >> 6;
        const size_t n0 = gr & 63;
        #pragma unroll
        for (int ct = 0; ct < 8; ++ct) {
            const int c = ct * 16 + lr;
            bf16x4 yv;
            #pragma unroll
            for (int r = 0; r < 4; ++r) yv[r] = (short)f2bf(acc[rf][ct][r]);
            *reinterpret_cast<bf16x4*>(Y1t + (b * CH + c) * NN + n0) = yv;
        }
    }
}

// ---------------------------------------------------------------------------
// Kernel 4: per-batch tail: H1=relu(A@Y1+b1); Y2=H1@W2; H2=relu(A@Y2+b2);
// out = H2.flat @ fcW + fcb.  256 thr = 4 waves; wave w owns dst rows w*16,
// all 128 cols (8 col-tiles). LDS 72.7 KB -> 2 blocks/CU.
// ---------------------------------------------------------------------------
__global__ __launch_bounds__(256, 2) void fused_rest(
    const ushort_t* __restrict__ Y1t,
    const ushort_t* __restrict__ Ah, const ushort_t* __restrict__ Al,
    const ushort_t* __restrict__ W2h, const ushort_t* __restrict__ W2l,
    const float* __restrict__ b1, const float* __restrict__ b2,
    const float* __restrict__ fcW, const float* __restrict__ fcb,
    float* __restrict__ out)
{
    __shared__ ushort_t sWh[128 * 72];   // 18432 B
    __shared__ ushort_t sWl[128 * 72];   // 18432 B
    __shared__ ushort_t sH1[64 * 136];   // 17408 B
    __shared__ ushort_t sYt[128 * 72];   // 18432 B (Y1t, later Y2t)
    __shared__ float sred[8];

    const int t  = threadIdx.x;
    const int l  = t & 63;
    const int w  = t >> 6;
    const int lr = l & 15;
    const int lk = l >> 4;
    const int b  = blockIdx.x;

    // ---- stage Y1t[b] (16 KB) ----
    {
        const ushort_t* src = Y1t + (size_t)b * CH * NN;
        #pragma unroll
        for (int u = 0; u < 4; ++u) {
            int e0 = (u * 256 + t) * 8;
            int c = e0 >> 6, n = e0 & 63;
            *reinterpret_cast<bf16x8*>(&sYt[c * 72 + n]) =
                *reinterpret_cast<const bf16x8*>(src + e0);
        }
    }
    // A-fragments (rows w*16..w*16+15), L2-resident
    bf16x8 ahf[2], alf[2];
    #pragma unroll
    for (int ks = 0; ks < 2; ++ks) {
        const int ko = ks * 32 + lk * 8;
        ahf[ks] = *reinterpret_cast<const bf16x8*>(Ah + (w * 16 + lr) * NN + ko);
        alf[ks] = *reinterpret_cast<const bf16x8*>(Al + (w * 16 + lr) * NN + ko);
    }
    __syncthreads();

    // ---- agg1: H1 = relu(A @ Y1 + b1) -> sH1 ----
    {
        f32x4 hacc[8];
        #pragma unroll
        for (int ct = 0; ct < 8; ++ct)
            #pragma unroll
            for (int i = 0; i < 4; ++i) hacc[ct][i] = 0.f;
        #pragma unroll
        for (int ks = 0; ks < 2; ++ks) {
            const int ko = ks * 32 + lk * 8;
            #pragma unroll
            for (int ct = 0; ct < 8; ++ct) {
                const int c = ct * 16 + lr;
                bf16x8 y = *reinterpret_cast<const bf16x8*>(&sYt[c * 72 + ko]);
                hacc[ct] = __builtin_amdgcn_mfma_f32_16x16x32_bf16(ahf[ks], y, hacc[ct], 0, 0, 0);
                hacc[ct] = __builtin_amdgcn_mfma_f32_16x16x32_bf16(alf[ks], y, hacc[ct], 0, 0, 0);
            }
        }
        #pragma unroll
        for (int ct = 0; ct < 8; ++ct) {
            const int c = ct * 16 + lr;
            const float bias = b1[c];
            #pragma unroll
            for (int r = 0; r < 4; ++r) {
                float v = fmaxf(hacc[ct][r] + bias, 0.f);
                sH1[(w * 16 + lk * 4 + r) * 136 + c] = f2bf(v);
            }
        }
    }
    __syncthreads();

    // ---- gemm2: Y2 = H1 @ W2 (2-pass W split) ----
    f32x4 acc2[8];
    #pragma unroll
    for (int ct = 0; ct < 8; ++ct)
        #pragma unroll
        for (int i = 0; i < 4; ++i) acc2[ct][i] = 0.f;

    for (int kc = 0; kc < 2; ++kc) {
        #pragma unroll
        for (int u = 0; u < 4; ++u) {
            int q = u * 256 + t, c = q >> 3, kq = (q & 7) * 8;
            *reinterpret_cast<bf16x8*>(&sWh[c * 72 + kq]) =
                *reinterpret_cast<const bf16x8*>(W2h + (size_t)c * CH + kc * 64 + kq);
            *reinterpret_cast<bf16x8*>(&sWl[c * 72 + kq]) =
                *reinterpret_cast<const bf16x8*>(W2l + (size_t)c * CH + kc * 64 + kq);
        }
        __syncthreads();
        #pragma unroll
        for (int ks = 0; ks < 2; ++ks) {
            const int ko = ks * 32 + lk * 8;
            bf16x8 hf = *reinterpret_cast<const bf16x8*>(&sH1[(w * 16 + lr) * 136 + kc * 64 + ko]);
            #pragma unroll
            for (int ct = 0; ct < 8; ++ct) {
                const int c = ct * 16 + lr;
                bf16x8 wh = *reinterpret_cast<const bf16x8*>(&sWh[c * 72 + ko]);
                bf16x8 wl = *reinterpret_cast<const bf16x8*>(&sWl[c * 72 + ko]);
                acc2[ct] = __builtin_amdgcn_mfma_f32_16x16x32_bf16(hf, wh, acc2[ct], 0, 0, 0);
                acc2[ct] = __builtin_amdgcn_mfma_f32_16x16x32_bf16(hf, wl, acc2[ct], 0, 0, 0);
            }
        }
        __syncthreads();
    }

    // ---- Y2 -> sYt (transposed; agg1 reads finished before gemm2 barriers) ----
    #pragma unroll
    for (int ct = 0; ct < 8; ++ct) {
        const int c = ct * 16 + lr;
        bf16x4 yv;
        #pragma unroll
        for (int r = 0; r < 4; ++r) yv[r] = (short)f2bf(acc2[ct][r]);
        *reinterpret_cast<bf16x4*>(&sYt[c * 72 + w * 16 + lk * 4]) = yv;
    }
    __syncthreads();

    // ---- agg2 + bias + relu + FC ----
    float p0 = 0.f, p1 = 0.f;
    {
        f32x4 h2[8];
        #pragma unroll
        for (int ct = 0; ct < 8; ++ct)
            #pragma unroll
            for (int i = 0; i < 4; ++i) h2[ct][i] = 0.f;
        #pragma unroll
        for (int ks = 0; ks < 2; ++ks) {
            const int ko = ks * 32 + lk * 8;
            #pragma unroll
            for (int ct = 0; ct < 8; ++ct) {
                const int c = ct * 16 + lr;
                bf16x8 y = *reinterpret_cast<const bf16x8*>(&sYt[c * 72 + ko]);
                h2[ct] = __builtin_amdgcn_mfma_f32_16x16x32_bf16(ahf[ks], y, h2[ct], 0, 0, 0);
                h2[ct] = __builtin_amdgcn_mfma_f32_16x16x32_bf16(alf[ks], y, h2[ct], 0, 0, 0);
            }
        }
        #pragma unroll
        for (int ct = 0; ct < 8; ++ct) {
            const int c = ct * 16 + lr;
            const float bias = b2[c];
            #pragma unroll
            for (int r = 0; r < 4; ++r) {
                const int n = w * 16 + lk * 4 + r;
                float v = fmaxf(h2[ct][r] + bias, 0.f);
                const float2 fw = *reinterpret_cast<const float2*>(fcW + ((size_t)(n * CH + c)) * 2);
                p0 = fmaf(v, fw.x, p0);
                p1 = fmaf(v, fw.y, p1);
            }
        }
    }
    #pragma unroll
    for (int off = 32; off > 0; off >>= 1) {
        p0 += __shfl_down(p0, off);
        p1 += __shfl_down(p1, off);
    }
    if (l == 0) { sred[w * 2] = p0; sred[w * 2 + 1] = p1; }
    __syncthreads();
    if (t == 0) {
        out[(size_t)b * 2 + 0] = sred[0] + sred[2] + sred[4] + sred[6] + fcb[0];
        out[(size_t)b * 2 + 1] = sred[1] + sred[3] + sred[5] + sred[7] + fcb[1];
    }
}

// ---------------------------------------------------------------------------
extern "C" void kernel_launch(void* const* d_in, const int* in_sizes, int n_in,
                              void* d_out, int out_size, void* d_ws, size_t ws_size,
                              hipStream_t stream) {
    const float* x   = (const float*)d_in[0];
    const int*   ei  = (const int*)d_in[1];
    const float* W1  = (const float*)d_in[2];
    const float* b1  = (const float*)d_in[3];
    const float* W2  = (const float*)d_in[4];
    const float* b2  = (const float*)d_in[5];
    const float* fcW = (const float*)d_in[6];
    const float* fcb = (const float*)d_in[7];
    float* outp = (float*)d_out;

    // ws layout (bf16 elems): Ah,Al [64*64]; W1t h,l [128*512]; W2t h,l [128*128]; Y1t [B*128*64]
    ushort_t* Ah  = (ushort_t*)d_ws;
    ushort_t* Al  = Ah + NN * NN;
    ushort_t* W1h = Al + NN * NN;
    ushort_t* W1l = W1h + CIN * CH;
    ushort_t* W2h = W1l + CIN * CH;
    ushort_t* W2l = W2h + CH * CH;
    ushort_t* Y1t = W2l + CH * CH;   // 33.55 MB

    const int E  = in_sizes[1] / 2;
    const int Bn = in_sizes[0] / (NN * CIN);

    build_adj<<<1, 256, 0, stream>>>(ei, E, Ah, Al);
    prep_w<<<64, 256, 0, stream>>>(W1, W2, W1h, W1l, W2h, W2l);
    gemm1_xw<<<Bn * NN / 128, 256, 0, stream>>>(x, W1h, W1l, Y1t);
    fused_rest<<<Bn, 256, 0, stream>>>(Y1t, Ah, Al, W2h, W2l, b1, b2, fcW, fcb, outp);
}

// Round 4
// 118.510 us; speedup vs baseline: 4.4558x; 1.0740x over previous
//
#include <hip/hip_runtime.h>
#include <cstddef>

// B=2048, N=64, C_IN=512, C_H=128, NUM_CLASSES=2, E=1024
#define NN   64
#define CIN  512
#define CH   128

typedef unsigned short ushort_t;
typedef __attribute__((ext_vector_type(8))) short bf16x8;
typedef __attribute__((ext_vector_type(4))) short bf16x4;
typedef __attribute__((ext_vector_type(4))) float f32x4;

__device__ __forceinline__ ushort_t f2bf(float f) {          // RN-even fp32->bf16
    union { float f; unsigned u; } v; v.f = f;
    unsigned r = v.u + 0x7fffu + ((v.u >> 16) & 1u);
    return (ushort_t)(r >> 16);
}
__device__ __forceinline__ float bf2f(ushort_t b) {
    union { unsigned u; float f; } v; v.u = ((unsigned)b) << 16;
    return v.f;
}

// ---------------------------------------------------------------------------
// Kernel 1: block 0 builds normalized adjacency A (hi/lo bf16); blocks 1..64
// transpose + hi/lo-split W1, W2. One launch instead of two.
// ---------------------------------------------------------------------------
__global__ __launch_bounds__(256) void prep_all(const int* __restrict__ ei, int E,
                                                const float* __restrict__ W1,
                                                const float* __restrict__ W2,
                                                ushort_t* __restrict__ Ah, ushort_t* __restrict__ Al,
                                                ushort_t* __restrict__ W1h, ushort_t* __restrict__ W1l,
                                                ushort_t* __restrict__ W2h, ushort_t* __restrict__ W2l) {
    const int t = threadIdx.x;
    if (blockIdx.x == 0) {
        __shared__ float sdeg[NN];
        __shared__ float snorm[NN];
        __shared__ float sA[NN * NN];
        if (t < NN) sdeg[t] = 0.f;
        for (int i = t; i < NN * NN; i += 256) sA[i] = 0.f;
        __syncthreads();
        for (int e = t; e < E; e += 256) atomicAdd(&sdeg[ei[E + e]], 1.0f);
        __syncthreads();
        if (t < NN) snorm[t] = rsqrtf(sdeg[t] + 1.0f);
        __syncthreads();
        for (int e = t; e < E; e += 256) {
            int s = ei[e], d = ei[E + e];
            atomicAdd(&sA[d * NN + s], snorm[s] * snorm[d]);
        }
        if (t < NN) atomicAdd(&sA[t * NN + t], snorm[t] * snorm[t]);
        __syncthreads();
        for (int i = t; i < NN * NN; i += 256) {
            float a = sA[i];
            ushort_t h = f2bf(a);
            Ah[i] = h;
            Al[i] = f2bf(a - bf2f(h));
        }
    } else {
        const int idx = (blockIdx.x - 1) * 256 + t;
        const int stride = 64 * 256;
        for (int i = idx; i < CIN * CH; i += stride) {
            int k = i / CH, c = i % CH;
            float v = W1[i];
            ushort_t h = f2bf(v);
            W1h[c * CIN + k] = h;
            W1l[c * CIN + k] = f2bf(v - bf2f(h));
        }
        for (int i = idx; i < CH * CH; i += stride) {
            int k = i / CH, c = i % CH;
            float v = W2[i];
            ushort_t h = f2bf(v);
            W2h[c * CH + k] = h;
            W2l[c * CH + k] = f2bf(v - bf2f(h));
        }
    }
}

// ---------------------------------------------------------------------------
// Kernel 2: streaming Y1 = X @ W1 (split-bf16, 3-pass).
// Grid 1024 x 256 thr (4 waves). Tile: 128 rows x 128 cols, K=512 in 8
// chunks of 64. W double-buffered in LDS w/ register prefetch.
// X PIPELINED ONE CHUNK AHEAD in registers: loads for chunk kc+1 are issued
// before chunk kc's MFMAs, converted to bf16 hi/lo at the top of chunk kc+1
// (~full chunk of latency cover; R3 issued them at the point of use).
// Output: Y1t[b][c][n] bf16 (per-batch transposed = agg1's B-frag layout).
// ---------------------------------------------------------------------------
__global__ __launch_bounds__(256, 2) void gemm1_xw(
    const float* __restrict__ x,
    const ushort_t* __restrict__ W1h, const ushort_t* __restrict__ W1l,
    ushort_t* __restrict__ Y1t)
{
    __shared__ ushort_t sW[2][2][128 * 72];   // [buf][h/l][c][k] 73728 B

    const int t  = threadIdx.x;
    const int l  = t & 63;
    const int w  = t >> 6;
    const int lr = l & 15;
    const int lk = l >> 4;
    const size_t rbase = (size_t)blockIdx.x * 128;

    const float* xp0 = x + (rbase + w * 32 + lr) * CIN + lk * 8;   // rf=0 base
    bf16x8 wreg[2][4];
    float4 xraw[2][2][2];                      // [rf][ks][half] next-chunk X

    // ---- prologue: issue X chunk 0, stage W chunk 0 ----
    #pragma unroll
    for (int rf = 0; rf < 2; ++rf) {
        const float* xp = xp0 + rf * 16 * CIN;
        xraw[rf][0][0] = *reinterpret_cast<const float4*>(xp);
        xraw[rf][0][1] = *reinterpret_cast<const float4*>(xp + 4);
        xraw[rf][1][0] = *reinterpret_cast<const float4*>(xp + 32);
        xraw[rf][1][1] = *reinterpret_cast<const float4*>(xp + 36);
    }
    #pragma unroll
    for (int u = 0; u < 4; ++u) {
        int q = u * 256 + t, c = q >> 3, kq = (q & 7) * 8;
        wreg[0][u] = *reinterpret_cast<const bf16x8*>(W1h + (size_t)c * CIN + kq);
        wreg[1][u] = *reinterpret_cast<const bf16x8*>(W1l + (size_t)c * CIN + kq);
    }
    #pragma unroll
    for (int u = 0; u < 4; ++u) {
        int q = u * 256 + t, c = q >> 3, kq = (q & 7) * 8;
        *reinterpret_cast<bf16x8*>(&sW[0][0][c * 72 + kq]) = wreg[0][u];
        *reinterpret_cast<bf16x8*>(&sW[0][1][c * 72 + kq]) = wreg[1][u];
    }
    __syncthreads();

    f32x4 acc[2][8];
    #pragma unroll
    for (int rf = 0; rf < 2; ++rf)
        #pragma unroll
        for (int ct = 0; ct < 8; ++ct)
            #pragma unroll
            for (int i = 0; i < 4; ++i) acc[rf][ct][i] = 0.f;

    for (int kc = 0; kc < 8; ++kc) {
        const int cur = kc & 1;

        // convert previously-loaded X (latency already covered) -> bf16 hi/lo
        bf16x8 xh[2][2], xl[2][2];
        #pragma unroll
        for (int rf = 0; rf < 2; ++rf) {
            #pragma unroll
            for (int ks = 0; ks < 2; ++ks) {
                const float xv[8] = {xraw[rf][ks][0].x, xraw[rf][ks][0].y,
                                     xraw[rf][ks][0].z, xraw[rf][ks][0].w,
                                     xraw[rf][ks][1].x, xraw[rf][ks][1].y,
                                     xraw[rf][ks][1].z, xraw[rf][ks][1].w};
                #pragma unroll
                for (int j = 0; j < 8; ++j) {
                    ushort_t h = f2bf(xv[j]);
                    xh[rf][ks][j] = (short)h;
                    xl[rf][ks][j] = (short)f2bf(xv[j] - bf2f(h));
                }
            }
        }
        // issue next-chunk X loads (HBM; covered by this chunk's compute)
        if (kc < 7) {
            #pragma unroll
            for (int rf = 0; rf < 2; ++rf) {
                const float* xp = xp0 + rf * 16 * CIN + (kc + 1) * 64;
                xraw[rf][0][0] = *reinterpret_cast<const float4*>(xp);
                xraw[rf][0][1] = *reinterpret_cast<const float4*>(xp + 4);
                xraw[rf][1][0] = *reinterpret_cast<const float4*>(xp + 32);
                xraw[rf][1][1] = *reinterpret_cast<const float4*>(xp + 36);
            }
            // issue next W chunk loads (L2-resident)
            #pragma unroll
            for (int u = 0; u < 4; ++u) {
                int q = u * 256 + t, c = q >> 3, kq = (q & 7) * 8;
                wreg[0][u] = *reinterpret_cast<const bf16x8*>(W1h + (size_t)c * CIN + (kc + 1) * 64 + kq);
                wreg[1][u] = *reinterpret_cast<const bf16x8*>(W1l + (size_t)c * CIN + (kc + 1) * 64 + kq);
            }
        }
        // compute chunk kc: B-frag LDS reads shared across both row-frags
        #pragma unroll
        for (int ks = 0; ks < 2; ++ks) {
            const int ko = ks * 32 + lk * 8;
            #pragma unroll
            for (int ct = 0; ct < 8; ++ct) {
                const int c = ct * 16 + lr;
                bf16x8 wh = *reinterpret_cast<const bf16x8*>(&sW[cur][0][c * 72 + ko]);
                bf16x8 wl = *reinterpret_cast<const bf16x8*>(&sW[cur][1][c * 72 + ko]);
                #pragma unroll
                for (int rf = 0; rf < 2; ++rf) {
                    acc[rf][ct] = __builtin_amdgcn_mfma_f32_16x16x32_bf16(xh[rf][ks], wh, acc[rf][ct], 0, 0, 0);
                    acc[rf][ct] = __builtin_amdgcn_mfma_f32_16x16x32_bf16(xl[rf][ks], wh, acc[rf][ct], 0, 0, 0);
                    acc[rf][ct] = __builtin_amdgcn_mfma_f32_16x16x32_bf16(xh[rf][ks], wl, acc[rf][ct], 0, 0, 0);
                }
            }
        }
        // write next W chunk into alternate buffer, one barrier per chunk
        if (kc < 7) {
            #pragma unroll
            for (int u = 0; u < 4; ++u) {
                int q = u * 256 + t, c = q >> 3, kq = (q & 7) * 8;
                *reinterpret_cast<bf16x8*>(&sW[cur ^ 1][0][c * 72 + kq]) = wreg[0][u];
                *reinterpret_cast<bf16x8*>(&sW[cur ^ 1][1][c * 72 + kq]) = wreg[1][u];
            }
        }
        __syncthreads();
    }

    // ---- store Y1t[b][c][n] (bf16x4 per fragment) ----
    #pragma unroll
    for (int rf = 0; rf < 2; ++rf) {
        const size_t gr = rbase + w * 32 + rf * 16 + lk * 4;
        const size_t b  = gr >> 6;
        const size_t n0 = gr & 63;
        #pragma unroll
        for (int ct = 0; ct < 8; ++ct) {
            const int c = ct * 16 + lr;
            bf16x4 yv;
            #pragma unroll
            for (int r = 0; r < 4; ++r) yv[r] = (short)f2bf(acc[rf][ct][r]);
            *reinterpret_cast<bf16x4*>(Y1t + (b * CH + c) * NN + n0) = yv;
        }
    }
}

// ---------------------------------------------------------------------------
// Kernel 3: per-batch tail: H1=relu(A@Y1+b1); Y2=H1@W2; H2=relu(A@Y2+b2);
// out = H2.flat @ fcW + fcb.  256 thr = 4 waves; wave w owns dst rows w*16,
// all 128 cols (8 col-tiles). LDS 72.7 KB -> 2 blocks/CU.
// ---------------------------------------------------------------------------
__global__ __launch_bounds__(256, 2) void fused_rest(
    const ushort_t* __restrict__ Y1t,
    const ushort_t* __restrict__ Ah, const ushort_t* __restrict__ Al,
    const ushort_t* __restrict__ W2h, const ushort_t* __restrict__ W2l,
    const float* __restrict__ b1, const float* __restrict__ b2,
    const float* __restrict__ fcW, const float* __restrict__ fcb,
    float* __restrict__ out)
{
    __shared__ ushort_t sWh[128 * 72];   // 18432 B
    __shared__ ushort_t sWl[128 * 72];   // 18432 B
    __shared__ ushort_t sH1[64 * 136];   // 17408 B
    __shared__ ushort_t sYt[128 * 72];   // 18432 B (Y1t, later Y2t)
    __shared__ float sred[8];

    const int t  = threadIdx.x;
    const int l  = t & 63;
    const int w  = t >> 6;
    const int lr = l & 15;
    const int lk = l >> 4;
    const int b  = blockIdx.x;

    // ---- stage Y1t[b] (16 KB) ----
    {
        const ushort_t* src = Y1t + (size_t)b * CH * NN;
        #pragma unroll
        for (int u = 0; u < 4; ++u) {
            int e0 = (u * 256 + t) * 8;
            int c = e0 >> 6, n = e0 & 63;
            *reinterpret_cast<bf16x8*>(&sYt[c * 72 + n]) =
                *reinterpret_cast<const bf16x8*>(src + e0);
        }
    }
    // A-fragments (rows w*16..w*16+15), L2-resident
    bf16x8 ahf[2], alf[2];
    #pragma unroll
    for (int ks = 0; ks < 2; ++ks) {
        const int ko = ks * 32 + lk * 8;
        ahf[ks] = *reinterpret_cast<const bf16x8*>(Ah + (w * 16 + lr) * NN + ko);
        alf[ks] = *reinterpret_cast<const bf16x8*>(Al + (w * 16 + lr) * NN + ko);
    }
    __syncthreads();

    // ---- agg1: H1 = relu(A @ Y1 + b1) -> sH1 ----
    {
        f32x4 hacc[8];
        #pragma unroll
        for (int ct = 0; ct < 8; ++ct)
            #pragma unroll
            for (int i = 0; i < 4; ++i) hacc[ct][i] = 0.f;
        #pragma unroll
        for (int ks = 0; ks < 2; ++ks) {
            const int ko = ks * 32 + lk * 8;
            #pragma unroll
            for (int ct = 0; ct < 8; ++ct) {
                const int c = ct * 16 + lr;
                bf16x8 y = *reinterpret_cast<const bf16x8*>(&sYt[c * 72 + ko]);
                hacc[ct] = __builtin_amdgcn_mfma_f32_16x16x32_bf16(ahf[ks], y, hacc[ct], 0, 0, 0);
                hacc[ct] = __builtin_amdgcn_mfma_f32_16x16x32_bf16(alf[ks], y, hacc[ct], 0, 0, 0);
            }
        }
        #pragma unroll
        for (int ct = 0; ct < 8; ++ct) {
            const int c = ct * 16 + lr;
            const float bias = b1[c];
            #pragma unroll
            for (int r = 0; r < 4; ++r) {
                float v = fmaxf(hacc[ct][r] + bias, 0.f);
                sH1[(w * 16 + lk * 4 + r) * 136 + c] = f2bf(v);
            }
        }
    }
    __syncthreads();

    // ---- gemm2: Y2 = H1 @ W2 (2-pass W split) ----
    f32x4 acc2[8];
    #pragma unroll
    for (int ct = 0; ct < 8; ++ct)
        #pragma unroll
        for (int i = 0; i < 4; ++i) acc2[ct][i] = 0.f;

    for (int kc = 0; kc < 2; ++kc) {
        #pragma unroll
        for (int u = 0; u < 4; ++u) {
            int q = u * 256 + t, c = q >> 3, kq = (q & 7) * 8;
            *reinterpret_cast<bf16x8*>(&sWh[c * 72 + kq]) =
                *reinterpret_cast<const bf16x8*>(W2h + (size_t)c * CH + kc * 64 + kq);
            *reinterpret_cast<bf16x8*>(&sWl[c * 72 + kq]) =
                *reinterpret_cast<const bf16x8*>(W2l + (size_t)c * CH + kc * 64 + kq);
        }
        __syncthreads();
        #pragma unroll
        for (int ks = 0; ks < 2; ++ks) {
            const int ko = ks * 32 + lk * 8;
            bf16x8 hf = *reinterpret_cast<const bf16x8*>(&sH1[(w * 16 + lr) * 136 + kc * 64 + ko]);
            #pragma unroll
            for (int ct = 0; ct < 8; ++ct) {
                const int c = ct * 16 + lr;
                bf16x8 wh = *reinterpret_cast<const bf16x8*>(&sWh[c * 72 + ko]);
                bf16x8 wl = *reinterpret_cast<const bf16x8*>(&sWl[c * 72 + ko]);
                acc2[ct] = __builtin_amdgcn_mfma_f32_16x16x32_bf16(hf, wh, acc2[ct], 0, 0, 0);
                acc2[ct] = __builtin_amdgcn_mfma_f32_16x16x32_bf16(hf, wl, acc2[ct], 0, 0, 0);
            }
        }
        __syncthreads();
    }

    // ---- Y2 -> sYt (transposed; agg1 reads finished before gemm2 barriers) ----
    #pragma unroll
    for (int ct = 0; ct < 8; ++ct) {
        const int c = ct * 16 + lr;
        bf16x4 yv;
        #pragma unroll
        for (int r = 0; r < 4; ++r) yv[r] = (short)f2bf(acc2[ct][r]);
        *reinterpret_cast<bf16x4*>(&sYt[c * 72 + w * 16 + lk * 4]) = yv;
    }
    __syncthreads();

    // ---- agg2 + bias + relu + FC ----
    float p0 = 0.f, p1 = 0.f;
    {
        f32x4 h2[8];
        #pragma unroll
        for (int ct = 0; ct < 8; ++ct)
            #pragma unroll
            for (int i = 0; i < 4; ++i) h2[ct][i] = 0.f;
        #pragma unroll
        for (int ks = 0; ks < 2; ++ks) {
            const int ko = ks * 32 + lk * 8;
            #pragma unroll
            for (int ct = 0; ct < 8; ++ct) {
                const int c = ct * 16 + lr;
                bf16x8 y = *reinterpret_cast<const bf16x8*>(&sYt[c * 72 + ko]);
                h2[ct] = __builtin_amdgcn_mfma_f32_16x16x32_bf16(ahf[ks], y, h2[ct], 0, 0, 0);
                h2[ct] = __builtin_amdgcn_mfma_f32_16x16x32_bf16(alf[ks], y, h2[ct], 0, 0, 0);
            }
        }
        #pragma unroll
        for (int ct = 0; ct < 8; ++ct) {
            const int c = ct * 16 + lr;
            const float bias = b2[c];
            #pragma unroll
            for (int r = 0; r < 4; ++r) {
                const int n = w * 16 + lk * 4 + r;
                float v = fmaxf(h2[ct][r] + bias, 0.f);
                const float2 fw = *reinterpret_cast<const float2*>(fcW + ((size_t)(n * CH + c)) * 2);
                p0 = fmaf(v, fw.x, p0);
                p1 = fmaf(v, fw.y, p1);
            }
        }
    }
    #pragma unroll
    for (int off = 32; off > 0; off >>= 1) {
        p0 += __shfl_down(p0, off);
        p1 += __shfl_down(p1, off);
    }
    if (l == 0) { sred[w * 2] = p0; sred[w * 2 + 1] = p1; }
    __syncthreads();
    if (t == 0) {
        out[(size_t)b * 2 + 0] = sred[0] + sred[2] + sred[4] + sred[6] + fcb[0];
        out[(size_t)b * 2 + 1] = sred[1] + sred[3] + sred[5] + sred[7] + fcb[1];
    }
}

// ---------------------------------------------------------------------------
extern "C" void kernel_launch(void* const* d_in, const int* in_sizes, int n_in,
                              void* d_out, int out_size, void* d_ws, size_t ws_size,
                              hipStream_t stream) {
    const float* x   = (const float*)d_in[0];
    const int*   ei  = (const int*)d_in[1];
    const float* W1  = (const float*)d_in[2];
    const float* b1  = (const float*)d_in[3];
    const float* W2  = (const float*)d_in[4];
    const float* b2  = (const float*)d_in[5];
    const float* fcW = (const float*)d_in[6];
    const float* fcb = (const float*)d_in[7];
    float* outp = (float*)d_out;

    // ws layout (bf16 elems): Ah,Al [64*64]; W1t h,l [128*512]; W2t h,l [128*128]; Y1t [B*128*64]
    ushort_t* Ah  = (ushort_t*)d_ws;
    ushort_t* Al  = Ah + NN * NN;
    ushort_t* W1h = Al + NN * NN;
    ushort_t* W1l = W1h + CIN * CH;
    ushort_t* W2h = W1l + CIN * CH;
    ushort_t* W2l = W2h + CH * CH;
    ushort_t* Y1t = W2l + CH * CH;   // 33.55 MB

    const int E  = in_sizes[1] / 2;
    const int Bn = in_sizes[0] / (NN * CIN);

    prep_all<<<65, 256, 0, stream>>>(ei, E, W1, W2, Ah, Al, W1h, W1l, W2h, W2l);
    gemm1_xw<<<Bn * NN / 128, 256, 0, stream>>>(x, W1h, W1l, Y1t);
    fused_rest<<<Bn, 256, 0, stream>>>(Y1t, Ah, Al, W2h, W2l, b1, b2, fcW, fcb, outp);
}

// Round 5
// 107.482 us; speedup vs baseline: 4.9130x; 1.1026x over previous
//
#include <hip/hip_runtime.h>
#include <cstddef>

// B=2048, N=64, C_IN=512, C_H=128, NUM_CLASSES=2, E=1024
#define NN   64
#define CIN  512
#define CH   128

typedef unsigned short ushort_t;
typedef __attribute__((ext_vector_type(8))) short bf16x8;
typedef __attribute__((ext_vector_type(4))) short bf16x4;
typedef __attribute__((ext_vector_type(4))) float f32x4;

__device__ __forceinline__ ushort_t f2bf(float f) {          // RN-even fp32->bf16
    union { float f; unsigned u; } v; v.f = f;
    unsigned r = v.u + 0x7fffu + ((v.u >> 16) & 1u);
    return (ushort_t)(r >> 16);
}
__device__ __forceinline__ float bf2f(ushort_t b) {
    union { unsigned u; float f; } v; v.u = ((unsigned)b) << 16;
    return v.f;
}

// ---------------------------------------------------------------------------
// Kernel 1: block 0 builds normalized adjacency A (hi/lo bf16); blocks 1..64
// transpose + hi/lo-split W1, W2.
// ---------------------------------------------------------------------------
__global__ __launch_bounds__(256) void prep_all(const int* __restrict__ ei, int E,
                                                const float* __restrict__ W1,
                                                const float* __restrict__ W2,
                                                ushort_t* __restrict__ Ah, ushort_t* __restrict__ Al,
                                                ushort_t* __restrict__ W1h, ushort_t* __restrict__ W1l,
                                                ushort_t* __restrict__ W2h, ushort_t* __restrict__ W2l) {
    const int t = threadIdx.x;
    if (blockIdx.x == 0) {
        __shared__ float sdeg[NN];
        __shared__ float snorm[NN];
        __shared__ float sA[NN * NN];
        if (t < NN) sdeg[t] = 0.f;
        for (int i = t; i < NN * NN; i += 256) sA[i] = 0.f;
        __syncthreads();
        for (int e = t; e < E; e += 256) atomicAdd(&sdeg[ei[E + e]], 1.0f);
        __syncthreads();
        if (t < NN) snorm[t] = rsqrtf(sdeg[t] + 1.0f);
        __syncthreads();
        for (int e = t; e < E; e += 256) {
            int s = ei[e], d = ei[E + e];
            atomicAdd(&sA[d * NN + s], snorm[s] * snorm[d]);
        }
        if (t < NN) atomicAdd(&sA[t * NN + t], snorm[t] * snorm[t]);
        __syncthreads();
        for (int i = t; i < NN * NN; i += 256) {
            float a = sA[i];
            ushort_t h = f2bf(a);
            Ah[i] = h;
            Al[i] = f2bf(a - bf2f(h));
        }
    } else {
        const int idx = (blockIdx.x - 1) * 256 + t;
        const int stride = 64 * 256;
        for (int i = idx; i < CIN * CH; i += stride) {
            int k = i / CH, c = i % CH;
            float v = W1[i];
            ushort_t h = f2bf(v);
            W1h[c * CIN + k] = h;
            W1l[c * CIN + k] = f2bf(v - bf2f(h));
        }
        for (int i = idx; i < CH * CH; i += stride) {
            int k = i / CH, c = i % CH;
            float v = W2[i];
            ushort_t h = f2bf(v);
            W2h[c * CH + k] = h;
            W2l[c * CH + k] = f2bf(v - bf2f(h));
        }
    }
}

// ---------------------------------------------------------------------------
// Kernel 2: FULLY FUSED. Each block: 128 rows = batches {2b, 2b+1}.
// Phase 1 (gemm1): Y1 = X @ W1, split-bf16 3-pass, W dbuf in LDS, X pipelined
//   one chunk ahead in registers (identical to R4).
// Phase 2 (tail, in-block): Y1->LDS; H1=relu(A@Y1+b1); Y2=H1@W2;
//   H2=relu(A@Y2+b2); out = H2.flat @ fcW + fcb. A/W2/fcW fragments JIT from
//   L2 (no LDS staging). LDS 73.7KB + sred -> 2 blocks/CU.
// Wave map phase1: wave w rows w*32 + rf*16. Phase2: q=w>>1 (batch), h=w&1
//   (row half): rows h*32 + rf*16 of batch q.
// LDS reuse: sYt[q] (2x9216 elem) = sW buf0; sH1[q] (2x8704 elem) at 18432+
//   aliases sW buf1 (dead after last chunk barrier; kc=7 reads buf1=cur(7&1=1)).
// ---------------------------------------------------------------------------
__global__ __launch_bounds__(256, 2) void fused_all(
    const float* __restrict__ x,
    const ushort_t* __restrict__ W1h, const ushort_t* __restrict__ W1l,
    const ushort_t* __restrict__ Ah, const ushort_t* __restrict__ Al,
    const ushort_t* __restrict__ W2h, const ushort_t* __restrict__ W2l,
    const float* __restrict__ b1, const float* __restrict__ b2,
    const float* __restrict__ fcW, const float* __restrict__ fcb,
    float* __restrict__ out)
{
    __shared__ ushort_t lds[36864];     // 73728 B
    __shared__ float sred[16];

    const int t  = threadIdx.x;
    const int l  = t & 63;
    const int w  = t >> 6;
    const int lr = l & 15;
    const int lk = l >> 4;
    const size_t rbase = (size_t)blockIdx.x * 128;

    const float* xp0 = x + (rbase + w * 32 + lr) * CIN + lk * 8;
    bf16x8 wreg[2][4];
    float4 xraw[2][2][2];

    // ---- prologue: issue X chunk 0, stage W chunk 0 ----
    #pragma unroll
    for (int rf = 0; rf < 2; ++rf) {
        const float* xp = xp0 + rf * 16 * CIN;
        xraw[rf][0][0] = *reinterpret_cast<const float4*>(xp);
        xraw[rf][0][1] = *reinterpret_cast<const float4*>(xp + 4);
        xraw[rf][1][0] = *reinterpret_cast<const float4*>(xp + 32);
        xraw[rf][1][1] = *reinterpret_cast<const float4*>(xp + 36);
    }
    #pragma unroll
    for (int u = 0; u < 4; ++u) {
        int q = u * 256 + t, c = q >> 3, kq = (q & 7) * 8;
        wreg[0][u] = *reinterpret_cast<const bf16x8*>(W1h + (size_t)c * CIN + kq);
        wreg[1][u] = *reinterpret_cast<const bf16x8*>(W1l + (size_t)c * CIN + kq);
    }
    #pragma unroll
    for (int u = 0; u < 4; ++u) {
        int q = u * 256 + t, c = q >> 3, kq = (q & 7) * 8;
        *reinterpret_cast<bf16x8*>(&lds[c * 72 + kq]) = wreg[0][u];            // buf0 hi
        *reinterpret_cast<bf16x8*>(&lds[9216 + c * 72 + kq]) = wreg[1][u];     // buf0 lo
    }
    __syncthreads();

    f32x4 acc[2][8];
    #pragma unroll
    for (int rf = 0; rf < 2; ++rf)
        #pragma unroll
        for (int ct = 0; ct < 8; ++ct)
            #pragma unroll
            for (int i = 0; i < 4; ++i) acc[rf][ct][i] = 0.f;

    for (int kc = 0; kc < 8; ++kc) {
        const int cur = kc & 1;
        const ushort_t* sWh = &lds[cur * 18432];
        const ushort_t* sWl = &lds[cur * 18432 + 9216];

        // convert previously-loaded X (latency covered) -> bf16 hi/lo
        bf16x8 xh[2][2], xl[2][2];
        #pragma unroll
        for (int rf = 0; rf < 2; ++rf) {
            #pragma unroll
            for (int ks = 0; ks < 2; ++ks) {
                const float xv[8] = {xraw[rf][ks][0].x, xraw[rf][ks][0].y,
                                     xraw[rf][ks][0].z, xraw[rf][ks][0].w,
                                     xraw[rf][ks][1].x, xraw[rf][ks][1].y,
                                     xraw[rf][ks][1].z, xraw[rf][ks][1].w};
                #pragma unroll
                for (int j = 0; j < 8; ++j) {
                    ushort_t hh = f2bf(xv[j]);
                    xh[rf][ks][j] = (short)hh;
                    xl[rf][ks][j] = (short)f2bf(xv[j] - bf2f(hh));
                }
            }
        }
        // issue next-chunk X loads (HBM; covered by this chunk's compute)
        if (kc < 7) {
            #pragma unroll
            for (int rf = 0; rf < 2; ++rf) {
                const float* xp = xp0 + rf * 16 * CIN + (kc + 1) * 64;
                xraw[rf][0][0] = *reinterpret_cast<const float4*>(xp);
                xraw[rf][0][1] = *reinterpret_cast<const float4*>(xp + 4);
                xraw[rf][1][0] = *reinterpret_cast<const float4*>(xp + 32);
                xraw[rf][1][1] = *reinterpret_cast<const float4*>(xp + 36);
            }
            #pragma unroll
            for (int u = 0; u < 4; ++u) {
                int q = u * 256 + t, c = q >> 3, kq = (q & 7) * 8;
                wreg[0][u] = *reinterpret_cast<const bf16x8*>(W1h + (size_t)c * CIN + (kc + 1) * 64 + kq);
                wreg[1][u] = *reinterpret_cast<const bf16x8*>(W1l + (size_t)c * CIN + (kc + 1) * 64 + kq);
            }
        }
        // compute chunk kc
        #pragma unroll
        for (int ks = 0; ks < 2; ++ks) {
            const int ko = ks * 32 + lk * 8;
            #pragma unroll
            for (int ct = 0; ct < 8; ++ct) {
                const int c = ct * 16 + lr;
                bf16x8 wh = *reinterpret_cast<const bf16x8*>(&sWh[c * 72 + ko]);
                bf16x8 wl = *reinterpret_cast<const bf16x8*>(&sWl[c * 72 + ko]);
                #pragma unroll
                for (int rf = 0; rf < 2; ++rf) {
                    acc[rf][ct] = __builtin_amdgcn_mfma_f32_16x16x32_bf16(xh[rf][ks], wh, acc[rf][ct], 0, 0, 0);
                    acc[rf][ct] = __builtin_amdgcn_mfma_f32_16x16x32_bf16(xl[rf][ks], wh, acc[rf][ct], 0, 0, 0);
                    acc[rf][ct] = __builtin_amdgcn_mfma_f32_16x16x32_bf16(xh[rf][ks], wl, acc[rf][ct], 0, 0, 0);
                }
            }
        }
        if (kc < 7) {
            const int nxt = cur ^ 1;
            #pragma unroll
            for (int u = 0; u < 4; ++u) {
                int q = u * 256 + t, c = q >> 3, kq = (q & 7) * 8;
                *reinterpret_cast<bf16x8*>(&lds[nxt * 18432 + c * 72 + kq]) = wreg[0][u];
                *reinterpret_cast<bf16x8*>(&lds[nxt * 18432 + 9216 + c * 72 + kq]) = wreg[1][u];
            }
        }
        __syncthreads();
    }

    // ================= tail (in-block) =================
    const int q = w >> 1;               // batch within block
    const int h = w & 1;                // row-half of the batch
    ushort_t* sYtq = &lds[q * 9216];            // [c][72] transposed Y
    ushort_t* sH1q = &lds[18432 + q * 8704];    // [n][136] H1 row-major

    // ---- Y1 (registers) -> sYt[q][c][n], bf16 ----
    #pragma unroll
    for (int rf = 0; rf < 2; ++rf) {
        const int n0 = h * 32 + rf * 16 + lk * 4;
        #pragma unroll
        for (int ct = 0; ct < 8; ++ct) {
            const int c = ct * 16 + lr;
            bf16x4 yv;
            #pragma unroll
            for (int r = 0; r < 4; ++r) yv[r] = (short)f2bf(acc[rf][ct][r]);
            *reinterpret_cast<bf16x4*>(&sYtq[c * 72 + n0]) = yv;
        }
    }
    __syncthreads();

    // ---- agg1: H1 = relu(A @ Y1 + b1) -> sH1 ----
    bf16x8 ahf[2][2], alf[2][2];        // [rf][ks]
    #pragma unroll
    for (int rf = 0; rf < 2; ++rf)
        #pragma unroll
        for (int ks = 0; ks < 2; ++ks) {
            const int nrow = h * 32 + rf * 16 + lr;
            const int ko = ks * 32 + lk * 8;
            ahf[rf][ks] = *reinterpret_cast<const bf16x8*>(Ah + nrow * NN + ko);
            alf[rf][ks] = *reinterpret_cast<const bf16x8*>(Al + nrow * NN + ko);
        }
    {
        f32x4 hacc[2][8];
        #pragma unroll
        for (int rf = 0; rf < 2; ++rf)
            #pragma unroll
            for (int ct = 0; ct < 8; ++ct)
                #pragma unroll
                for (int i = 0; i < 4; ++i) hacc[rf][ct][i] = 0.f;
        #pragma unroll
        for (int ks = 0; ks < 2; ++ks) {
            const int ko = ks * 32 + lk * 8;
            #pragma unroll
            for (int ct = 0; ct < 8; ++ct) {
                const int c = ct * 16 + lr;
                bf16x8 y = *reinterpret_cast<const bf16x8*>(&sYtq[c * 72 + ko]);
                #pragma unroll
                for (int rf = 0; rf < 2; ++rf) {
                    hacc[rf][ct] = __builtin_amdgcn_mfma_f32_16x16x32_bf16(ahf[rf][ks], y, hacc[rf][ct], 0, 0, 0);
                    hacc[rf][ct] = __builtin_amdgcn_mfma_f32_16x16x32_bf16(alf[rf][ks], y, hacc[rf][ct], 0, 0, 0);
                }
            }
        }
        #pragma unroll
        for (int rf = 0; rf < 2; ++rf)
            #pragma unroll
            for (int ct = 0; ct < 8; ++ct) {
                const int c = ct * 16 + lr;
                const float bias = b1[c];
                #pragma unroll
                for (int r = 0; r < 4; ++r) {
                    const int n = h * 32 + rf * 16 + lk * 4 + r;
                    float v = fmaxf(hacc[rf][ct][r] + bias, 0.f);
                    sH1q[n * 136 + c] = f2bf(v);
                }
            }
    }
    __syncthreads();

    // ---- gemm2: Y2 = H1 @ W2 (2-pass W split), W2 frags JIT from L2 ----
    f32x4 acc2[2][8];
    #pragma unroll
    for (int rf = 0; rf < 2; ++rf)
        #pragma unroll
        for (int ct = 0; ct < 8; ++ct)
            #pragma unroll
            for (int i = 0; i < 4; ++i) acc2[rf][ct][i] = 0.f;
    {
        bf16x8 hf[2][4];                // [rf][ks]  K=128
        #pragma unroll
        for (int rf = 0; rf < 2; ++rf)
            #pragma unroll
            for (int ks = 0; ks < 4; ++ks)
                hf[rf][ks] = *reinterpret_cast<const bf16x8*>(
                    &sH1q[(h * 32 + rf * 16 + lr) * 136 + ks * 32 + lk * 8]);
        #pragma unroll
        for (int ct = 0; ct < 8; ++ct) {
            const int c = ct * 16 + lr;
            bf16x8 w2h[4], w2l[4];
            #pragma unroll
            for (int ks = 0; ks < 4; ++ks) {
                const int ko = ks * 32 + lk * 8;
                w2h[ks] = *reinterpret_cast<const bf16x8*>(W2h + (size_t)c * CH + ko);
                w2l[ks] = *reinterpret_cast<const bf16x8*>(W2l + (size_t)c * CH + ko);
            }
            #pragma unroll
            for (int ks = 0; ks < 4; ++ks)
                #pragma unroll
                for (int rf = 0; rf < 2; ++rf) {
                    acc2[rf][ct] = __builtin_amdgcn_mfma_f32_16x16x32_bf16(hf[rf][ks], w2h[ks], acc2[rf][ct], 0, 0, 0);
                    acc2[rf][ct] = __builtin_amdgcn_mfma_f32_16x16x32_bf16(hf[rf][ks], w2l[ks], acc2[rf][ct], 0, 0, 0);
                }
        }
    }
    // Y2 -> sYt[q] (transposed); all sYt(agg1) reads finished at last barrier
    #pragma unroll
    for (int rf = 0; rf < 2; ++rf) {
        const int n0 = h * 32 + rf * 16 + lk * 4;
        #pragma unroll
        for (int ct = 0; ct < 8; ++ct) {
            const int c = ct * 16 + lr;
            bf16x4 yv;
            #pragma unroll
            for (int r = 0; r < 4; ++r) yv[r] = (short)f2bf(acc2[rf][ct][r]);
            *reinterpret_cast<bf16x4*>(&sYtq[c * 72 + n0]) = yv;
        }
    }
    __syncthreads();

    // ---- agg2 + bias + relu + FC ----
    float p0 = 0.f, p1 = 0.f;
    {
        f32x4 h2[2][8];
        #pragma unroll
        for (int rf = 0; rf < 2; ++rf)
            #pragma unroll
            for (int ct = 0; ct < 8; ++ct)
                #pragma unroll
                for (int i = 0; i < 4; ++i) h2[rf][ct][i] = 0.f;
        #pragma unroll
        for (int ks = 0; ks < 2; ++ks) {
            const int ko = ks * 32 + lk * 8;
            #pragma unroll
            for (int ct = 0; ct < 8; ++ct) {
                const int c = ct * 16 + lr;
                bf16x8 y = *reinterpret_cast<const bf16x8*>(&sYtq[c * 72 + ko]);
                #pragma unroll
                for (int rf = 0; rf < 2; ++rf) {
                    h2[rf][ct] = __builtin_amdgcn_mfma_f32_16x16x32_bf16(ahf[rf][ks], y, h2[rf][ct], 0, 0, 0);
                    h2[rf][ct] = __builtin_amdgcn_mfma_f32_16x16x32_bf16(alf[rf][ks], y, h2[rf][ct], 0, 0, 0);
                }
            }
        }
        #pragma unroll
        for (int rf = 0; rf < 2; ++rf)
            #pragma unroll
            for (int ct = 0; ct < 8; ++ct) {
                const int c = ct * 16 + lr;
                const float bias = b2[c];
                #pragma unroll
                for (int r = 0; r < 4; ++r) {
                    const int n = h * 32 + rf * 16 + lk * 4 + r;
                    float v = fmaxf(h2[rf][ct][r] + bias, 0.f);
                    const float2 fw = *reinterpret_cast<const float2*>(fcW + ((size_t)(n * CH + c)) * 2);
                    p0 = fmaf(v, fw.x, p0);
                    p1 = fmaf(v, fw.y, p1);
                }
            }
    }
    #pragma unroll
    for (int off = 32; off > 0; off >>= 1) {
        p0 += __shfl_down(p0, off);
        p1 += __shfl_down(p1, off);
    }
    if (l == 0) { sred[w * 2] = p0; sred[w * 2 + 1] = p1; }
    __syncthreads();
    if (t == 0) {
        const size_t bA = (size_t)blockIdx.x * 2;
        out[bA * 2 + 0]       = sred[0] + sred[2] + fcb[0];
        out[bA * 2 + 1]       = sred[1] + sred[3] + fcb[1];
        out[(bA + 1) * 2 + 0] = sred[4] + sred[6] + fcb[0];
        out[(bA + 1) * 2 + 1] = sred[5] + sred[7] + fcb[1];
    }
}

// ---------------------------------------------------------------------------
extern "C" void kernel_launch(void* const* d_in, const int* in_sizes, int n_in,
                              void* d_out, int out_size, void* d_ws, size_t ws_size,
                              hipStream_t stream) {
    const float* x   = (const float*)d_in[0];
    const int*   ei  = (const int*)d_in[1];
    const float* W1  = (const float*)d_in[2];
    const float* b1  = (const float*)d_in[3];
    const float* W2  = (const float*)d_in[4];
    const float* b2  = (const float*)d_in[5];
    const float* fcW = (const float*)d_in[6];
    const float* fcb = (const float*)d_in[7];
    float* outp = (float*)d_out;

    // ws layout (bf16 elems): Ah,Al [64*64]; W1t h,l [128*512]; W2t h,l [128*128]
    ushort_t* Ah  = (ushort_t*)d_ws;
    ushort_t* Al  = Ah + NN * NN;
    ushort_t* W1h = Al + NN * NN;
    ushort_t* W1l = W1h + CIN * CH;
    ushort_t* W2h = W1l + CIN * CH;
    ushort_t* W2l = W2h + CH * CH;     // total 344064 B

    const int E  = in_sizes[1] / 2;
    const int Bn = in_sizes[0] / (NN * CIN);

    prep_all<<<65, 256, 0, stream>>>(ei, E, W1, W2, Ah, Al, W1h, W1l, W2h, W2l);
    fused_all<<<Bn / 2, 256, 0, stream>>>(x, W1h, W1l, Ah, Al, W2h, W2l,
                                          b1, b2, fcW, fcb, outp);
}